// Round 1
// baseline (3371.314 us; speedup 1.0000x reference)
//
#include <hip/hip_runtime.h>
#include <hip/hip_bf16.h>
#include <math.h>

#define NROWSQ 32768   // rows per input
#define RTOT   65536   // total rows (mean ++ std)
#define DDIM   512
#define KC     4096

#define BM  128        // rows per block tile
#define BKT 128        // codes per k-tile
#define DT  16         // d-chunk staged per iteration

// ---- workspace layout (bytes) ----
#define WS_INDS 0               // 65536 * int
#define WS_HIST 262144          // 8192 * int (hist_mean[4096] ++ hist_std[4096])
#define WS_PC1  294912          // 1024 * double
#define WS_PC2  303104          // 1024 * double
#define WS_PKL  311296          // 1024 * double
#define WS_XSQ  319488          // 65536 * float
#define WS_ESQ  581632          // 4096 * float

// ---------------------------------------------------------------------------
// Kernel 0: per-row sum of squares (f32), one wave per row.
// ---------------------------------------------------------------------------
__global__ __launch_bounds__(256) void rowsq_kernel(const float* __restrict__ src,
                                                    float* __restrict__ dst,
                                                    int nrows)
{
    int row  = blockIdx.x * 4 + (threadIdx.x >> 6);
    int lane = threadIdx.x & 63;
    if (row >= nrows) return;
    const float* p = src + (size_t)row * DDIM;
    float4 v1 = *(const float4*)&p[lane * 4];
    float4 v2 = *(const float4*)&p[256 + lane * 4];
    float s = v1.x*v1.x + v1.y*v1.y + v1.z*v1.z + v1.w*v1.w
            + v2.x*v2.x + v2.y*v2.y + v2.z*v2.z + v2.w*v2.w;
    #pragma unroll
    for (int off = 1; off < 64; off <<= 1) s += __shfl_xor(s, off);
    if (lane == 0) dst[row] = s;
}

// ---------------------------------------------------------------------------
// Kernel 1: fused distance GEMM + running argmin.
// Block computes a 128-row stripe against ALL 4096 codes.
// dist replicated in reference rounding order: fl(fl(xsq+esq) - fl(2*dot)).
// Tie-break: smallest code index (matches jnp.argmin first-occurrence).
// ---------------------------------------------------------------------------
__global__ __launch_bounds__(256) void argmin_kernel(
    const float* __restrict__ xmean, const float* __restrict__ xstd,
    const float* __restrict__ emb,
    const float* __restrict__ xsq, const float* __restrict__ esq,
    int* __restrict__ inds)
{
    __shared__ float As[DT][BM];     // A tile, d-major
    __shared__ float Bs[DT][BKT];    // B tile, d-major
    __shared__ float redv[BM][17];
    __shared__ int   redi[BM][17];

    const int blk  = blockIdx.x;          // 0..511
    const int row0 = blk * BM;            // global row (0..65535)
    const float* X = (row0 < NROWSQ) ? xmean : xstd;
    const int xrow0 = (row0 < NROWSQ) ? row0 : row0 - NROWSQ;

    const int t  = threadIdx.x;
    const int tr = t & 15;                // row group
    const int tc = t >> 4;                // col group

    float minv[8];
    int   mini[8];
    #pragma unroll
    for (int i = 0; i < 8; i++) { minv[i] = INFINITY; mini[i] = 0; }

    float xs[8];
    #pragma unroll
    for (int i = 0; i < 8; i++) {
        int rl = (i < 4) ? (tr * 4 + i) : (64 + tr * 4 + (i - 4));
        xs[i] = xsq[row0 + rl];
    }

    for (int kt = 0; kt < KC; kt += BKT) {
        float acc[8][8];
        #pragma unroll
        for (int i = 0; i < 8; i++)
            #pragma unroll
            for (int j = 0; j < 8; j++) acc[i][j] = 0.0f;

        for (int d0 = 0; d0 < DDIM; d0 += DT) {
            __syncthreads();
            // stage A and B: 2048 floats each, 2 float4 per thread
            #pragma unroll
            for (int s = 0; s < 2; s++) {
                int i  = t + s * 256;     // 0..511
                int r  = i >> 2;          // 0..127
                int dq = i & 3;           // 0..3 (which float4 within the 16-wide d chunk)
                float4 va = *(const float4*)&X[(size_t)(xrow0 + r) * DDIM + d0 + dq * 4];
                As[dq * 4 + 0][r] = va.x; As[dq * 4 + 1][r] = va.y;
                As[dq * 4 + 2][r] = va.z; As[dq * 4 + 3][r] = va.w;
                float4 vb = *(const float4*)&emb[(size_t)(kt + r) * DDIM + d0 + dq * 4];
                Bs[dq * 4 + 0][r] = vb.x; Bs[dq * 4 + 1][r] = vb.y;
                Bs[dq * 4 + 2][r] = vb.z; Bs[dq * 4 + 3][r] = vb.w;
            }
            __syncthreads();

            #pragma unroll
            for (int d = 0; d < DT; d++) {
                float4 a0 = *(const float4*)&As[d][tr * 4];
                float4 a1 = *(const float4*)&As[d][64 + tr * 4];
                float4 b0 = *(const float4*)&Bs[d][tc * 4];
                float4 b1 = *(const float4*)&Bs[d][64 + tc * 4];
                float av[8] = {a0.x, a0.y, a0.z, a0.w, a1.x, a1.y, a1.z, a1.w};
                float bv[8] = {b0.x, b0.y, b0.z, b0.w, b1.x, b1.y, b1.z, b1.w};
                #pragma unroll
                for (int i = 0; i < 8; i++)
                    #pragma unroll
                    for (int j = 0; j < 8; j++)
                        acc[i][j] = fmaf(av[i], bv[j], acc[i][j]);
            }
        }

        // epilogue: dist + running argmin (cols ascend within thread -> tie=first idx)
        #pragma unroll
        for (int j = 0; j < 8; j++) {
            int c = kt + ((j < 4) ? (tc * 4 + j) : (64 + tc * 4 + (j - 4)));
            float eq = esq[c];
            #pragma unroll
            for (int i = 0; i < 8; i++) {
                float dist = (xs[i] + eq) - 2.0f * acc[i][j];
                if (dist < minv[i]) { minv[i] = dist; mini[i] = c; }
            }
        }
    }

    // cross-thread reduce per row (16 column-group candidates per row)
    #pragma unroll
    for (int i = 0; i < 8; i++) {
        int rl = (i < 4) ? (tr * 4 + i) : (64 + tr * 4 + (i - 4));
        redv[rl][tc] = minv[i];
        redi[rl][tc] = mini[i];
    }
    __syncthreads();
    if (t < BM) {
        float bv = redv[t][0];
        int   bi = redi[t][0];
        #pragma unroll 1
        for (int c = 1; c < 16; c++) {
            float v = redv[t][c];
            int   ii = redi[t][c];
            if (v < bv || (v == bv && ii < bi)) { bv = v; bi = ii; }
        }
        inds[row0 + t] = bi;
    }
}

// ---------------------------------------------------------------------------
// Kernel 2: gather quantized rows to outputs + commitment/KL partials + hist.
// One wave per row; 1024 blocks x 256 threads; 32 rows/block.
// ---------------------------------------------------------------------------
__global__ __launch_bounds__(256) void gather_stats_kernel(
    const float* __restrict__ xmean, const float* __restrict__ xstd,
    const float* __restrict__ emb, const int* __restrict__ inds,
    float* __restrict__ out0, float* __restrict__ out1,
    int* __restrict__ hist,
    double* __restrict__ pc1, double* __restrict__ pc2, double* __restrict__ pkl)
{
    const int blk  = blockIdx.x;          // 0..1023
    const int w    = threadIdx.x >> 6;    // wave 0..3
    const int lane = threadIdx.x & 63;

    float c1 = 0.0f, c2 = 0.0f, kls = 0.0f;

    for (int j = 0; j < 8; j++) {
        int n  = blk * 32 + j * 4 + w;    // 0..32767
        int im = inds[n];
        int is = inds[NROWSQ + n];
        if (lane == 0) {
            atomicAdd(&hist[im], 1);
            atomicAdd(&hist[KC + is], 1);
        }
        const float* em = emb  + (size_t)im * DDIM;
        const float* es = emb  + (size_t)is * DDIM;
        const float* xm = xmean + (size_t)n * DDIM;
        const float* xv = xstd  + (size_t)n * DDIM;

        float t1 = 0.0f, t2 = 0.0f;
        float pp = 1.0f, pq = 1.0f;

        #pragma unroll
        for (int half = 0; half < 2; half++) {
            int d = half * 256 + lane * 4;
            float4 q4  = *(const float4*)&em[d];
            float4 m4  = *(const float4*)&xm[d];
            float4 qs4 = *(const float4*)&es[d];
            float4 s4  = *(const float4*)&xv[d];
            float qa[4] = {q4.x, q4.y, q4.z, q4.w};
            float ma[4] = {m4.x, m4.y, m4.z, m4.w};
            float qb[4] = {qs4.x, qs4.y, qs4.z, qs4.w};
            float sa[4] = {s4.x, s4.y, s4.z, s4.w};
            float o0[4], o1[4];
            #pragma unroll
            for (int u = 0; u < 4; u++) {
                float q = qa[u], m = ma[u], s = sa[u], qq = qb[u];
                o0[u] = m + (q - m);            // straight-through forward value
                o1[u] = qq;
                float du = q - m;
                c1 += du * du;
                float dsv = qq - s; c2 += dsv * dsv;
                float sp = s * s, sq = qq * qq;
                float iq = 1.0f / sq;
                t1 += sp * iq;
                t2 += du * du * iq;
                pp *= sp; pq *= sq;
            }
            *(float4*)&out0[(size_t)n * DDIM + d] = make_float4(o0[0], o0[1], o0[2], o0[3]);
            *(float4*)&out1[(size_t)n * DDIM + d] = make_float4(o1[0], o1[1], o1[2], o1[3]);
        }

        // wave reduce: sums and products
        #pragma unroll
        for (int off = 1; off < 64; off <<= 1) {
            t1 += __shfl_xor(t1, off);
            t2 += __shfl_xor(t2, off);
            pp *= __shfl_xor(pp, off);
            pq *= __shfl_xor(pq, off);
        }
        if (lane == 0) {
            float term4 = logf(pq + 1e-8f) - logf(pp + 1e-8f);
            float kl = 0.5f * (t1 + t2 - (float)DDIM + term4);
            // jnp.clip semantics: NaN propagates
            float klc = kl < 0.0f ? 0.0f : (kl > 10.0f ? 10.0f : kl);
            kls += klc;
        }
    }

    #pragma unroll
    for (int off = 1; off < 64; off <<= 1) {
        c1 += __shfl_xor(c1, off);
        c2 += __shfl_xor(c2, off);
    }
    __shared__ double sc1[4], sc2[4], skl[4];
    if (lane == 0) { sc1[w] = (double)c1; sc2[w] = (double)c2; skl[w] = (double)kls; }
    __syncthreads();
    if (threadIdx.x == 0) {
        pc1[blk] = sc1[0] + sc1[1] + sc1[2] + sc1[3];
        pc2[blk] = sc2[0] + sc2[1] + sc2[2] + sc2[3];
        pkl[blk] = skl[0] + skl[1] + skl[2] + skl[3];
    }
}

// ---------------------------------------------------------------------------
// Kernel 3: finalize scalars.
// ---------------------------------------------------------------------------
__global__ __launch_bounds__(256) void finalize_kernel(
    const int* __restrict__ hist,
    const double* __restrict__ pc1, const double* __restrict__ pc2,
    const double* __restrict__ pkl,
    float* __restrict__ out)
{
    int t = threadIdx.x;
    int w = t >> 6, lane = t & 63;

    double a = 0.0, b = 0.0, c = 0.0;
    for (int i = t; i < 1024; i += 256) { a += pc1[i]; b += pc2[i]; c += pkl[i]; }

    float hm = 0.0f, hs = 0.0f;
    for (int k = t; k < KC; k += 256) {
        float p  = (float)hist[k]      * (1.0f / 32768.0f);
        hm += p * logf(p + 1e-10f);
        float p2 = (float)hist[KC + k] * (1.0f / 32768.0f);
        hs += p2 * logf(p2 + 1e-10f);
    }

    #pragma unroll
    for (int off = 1; off < 64; off <<= 1) {
        a  += __shfl_xor(a, off);
        b  += __shfl_xor(b, off);
        c  += __shfl_xor(c, off);
        hm += __shfl_xor(hm, off);
        hs += __shfl_xor(hs, off);
    }
    __shared__ double sa[4], sb[4], sc[4];
    __shared__ float  sm[4], ss[4];
    if (lane == 0) { sa[w] = a; sb[w] = b; sc[w] = c; sm[w] = hm; ss[w] = hs; }
    __syncthreads();
    if (t == 0) {
        double A = sa[0] + sa[1] + sa[2] + sa[3];
        double B = sb[0] + sb[1] + sb[2] + sb[3];
        double C = sc[0] + sc[1] + sc[2] + sc[3];
        float HM = sm[0] + sm[1] + sm[2] + sm[3];
        float HS = ss[0] + ss[1] + ss[2] + ss[3];
        float mean1 = (float)(A * (1.0 / 16777216.0));
        float mean2 = (float)(B * (1.0 / 16777216.0));
        float commitment = mean1 + mean2;
        float el = (float)(C * (1.0 / 32768.0));
        out[33554432] = commitment * 0.25f + el;   // vq_loss
        out[33554433] = expf(-HM);                 // perplexity_mean
        out[33554434] = expf(-HS);                 // perplexity_std
    }
}

// ---------------------------------------------------------------------------
extern "C" void kernel_launch(void* const* d_in, const int* in_sizes, int n_in,
                              void* d_out, int out_size, void* d_ws, size_t ws_size,
                              hipStream_t stream)
{
    const float* xmean = (const float*)d_in[0];
    const float* xstd  = (const float*)d_in[1];
    const float* emb   = (const float*)d_in[2];
    float* out = (float*)d_out;
    char*  ws  = (char*)d_ws;

    int*    inds = (int*)(ws + WS_INDS);
    int*    hist = (int*)(ws + WS_HIST);
    double* pc1  = (double*)(ws + WS_PC1);
    double* pc2  = (double*)(ws + WS_PC2);
    double* pkl  = (double*)(ws + WS_PKL);
    float*  xsq  = (float*)(ws + WS_XSQ);
    float*  esq  = (float*)(ws + WS_ESQ);

    hipMemsetAsync(hist, 0, 2 * KC * sizeof(int), stream);

    rowsq_kernel<<<NROWSQ / 4, 256, 0, stream>>>(xmean, xsq, NROWSQ);
    rowsq_kernel<<<NROWSQ / 4, 256, 0, stream>>>(xstd, xsq + NROWSQ, NROWSQ);
    rowsq_kernel<<<KC / 4, 256, 0, stream>>>(emb, esq, KC);

    argmin_kernel<<<RTOT / BM, 256, 0, stream>>>(xmean, xstd, emb, xsq, esq, inds);

    gather_stats_kernel<<<1024, 256, 0, stream>>>(xmean, xstd, emb, inds,
                                                  out, out + (size_t)NROWSQ * DDIM,
                                                  hist, pc1, pc2, pkl);

    finalize_kernel<<<1, 256, 0, stream>>>(hist, pc1, pc2, pkl, out);
}

// Round 2
// 1897.869 us; speedup vs baseline: 1.7764x; 1.7764x over previous
//
#include <hip/hip_runtime.h>
#include <math.h>

#define NROWSQ 32768   // rows per input
#define RTOT   65536   // total rows (mean ++ std)
#define DDIM   512
#define KC     4096

#define CAP    32          // candidate list capacity per row
#define WMARG  1.25e-3f    // candidate window (provably > 2*err + quantization)
#define ESCALE 8192.0f     // 2^13, exact; keeps f16(e) out of denormal range
#define EPSC   0.000244140625f   // 2/8192 = 2^-12: dist = (xs+eq) - EPSC*acc

typedef __attribute__((ext_vector_type(8))) _Float16 half8;
typedef __attribute__((ext_vector_type(4))) float f32x4;

// ---- workspace layout (bytes) ----
#define WS_INDS 0               // 65536 * int
#define WS_HIST 262144          // 8192 * int
#define WS_PC1  294912          // 1024 * double
#define WS_PC2  303104          // 1024 * double
#define WS_PKL  311296          // 1024 * double
#define WS_XSQ  319488          // 65536 * float
#define WS_ESQ  581632          // 4096 * float
#define WS_EF16 598016          // 4096*512 * u16 (scaled f16 embedding)
#define WS_EF16_END (598016 + KC * DDIM * 2)

__device__ __forceinline__ uint2 pack4_f16(float4 v, float s) {
    _Float16 h0 = (_Float16)(v.x * s);
    _Float16 h1 = (_Float16)(v.y * s);
    _Float16 h2 = (_Float16)(v.z * s);
    _Float16 h3 = (_Float16)(v.w * s);
    uint2 r;
    r.x = (unsigned int)__builtin_bit_cast(unsigned short, h0)
        | ((unsigned int)__builtin_bit_cast(unsigned short, h1) << 16);
    r.y = (unsigned int)__builtin_bit_cast(unsigned short, h2)
        | ((unsigned int)__builtin_bit_cast(unsigned short, h3) << 16);
    return r;
}

// ---------------------------------------------------------------------------
// Kernel 0: per-row sum of squares (f32), one wave per row. (unchanged)
// ---------------------------------------------------------------------------
__global__ __launch_bounds__(256) void rowsq_kernel(const float* __restrict__ src,
                                                    float* __restrict__ dst,
                                                    int nrows)
{
    int row  = blockIdx.x * 4 + (threadIdx.x >> 6);
    int lane = threadIdx.x & 63;
    if (row >= nrows) return;
    const float* p = src + (size_t)row * DDIM;
    float4 v1 = *(const float4*)&p[lane * 4];
    float4 v2 = *(const float4*)&p[256 + lane * 4];
    float s = v1.x*v1.x + v1.y*v1.y + v1.z*v1.z + v1.w*v1.w
            + v2.x*v2.x + v2.y*v2.y + v2.z*v2.z + v2.w*v2.w;
    #pragma unroll
    for (int off = 1; off < 64; off <<= 1) s += __shfl_xor(s, off);
    if (lane == 0) dst[row] = s;
}

// ---------------------------------------------------------------------------
// Kernel 0b: convert embedding to scaled f16 (used when ws_size permits).
// ---------------------------------------------------------------------------
__global__ __launch_bounds__(256) void cvt_e_kernel(const float* __restrict__ emb,
                                                    unsigned short* __restrict__ ef)
{
    int i = (blockIdx.x * 256 + threadIdx.x) * 4;
    float4 v = *(const float4*)&emb[i];
    *(uint2*)&ef[i] = pack4_f16(v, ESCALE);
}

// ---------------------------------------------------------------------------
// Kernel 1: f16-MFMA distance screen + candidate collect + exact f32 rescore.
// Block = 128 rows x all 4096 codes (32 code-tiles of 128).
// ---------------------------------------------------------------------------
template<bool EF16>
__global__ __launch_bounds__(256, 2) void mfma_argmin_kernel(
    const float* __restrict__ xmean, const float* __restrict__ xstd,
    const float* __restrict__ emb, const unsigned short* __restrict__ ef,
    const float* __restrict__ xsq, const float* __restrict__ esq,
    int* __restrict__ inds)
{
    __shared__ unsigned short As[128 * 64];   // f16 bits, XOR-swizzled
    __shared__ unsigned short Bs[128 * 64];
    __shared__ unsigned int   rowmin[128];
    __shared__ int            ccnt[128];
    __shared__ unsigned short cand[128 * CAP];
    __shared__ unsigned long long best[128];

    const int t    = threadIdx.x;
    const int lane = t & 63;
    const int wid  = t >> 6;
    const int wr   = wid >> 1, wc = wid & 1;
    const int row0 = blockIdx.x * 128;
    const float* X = (row0 < NROWSQ) ? xmean : xstd;
    const int xrow0 = (row0 < NROWSQ) ? row0 : row0 - NROWSQ;

    if (t < 128) { rowmin[t] = 0x7f800000u; ccnt[t] = 0; best[t] = ~0ull; }

    float xs[16];
    #pragma unroll
    for (int fr = 0; fr < 4; ++fr)
        #pragma unroll
        for (int q = 0; q < 4; ++q)
            xs[fr*4+q] = xsq[row0 + wr*64 + fr*16 + (lane>>4)*4 + q];

    for (int ct = 0; ct < 32; ++ct) {
        f32x4 acc[4][4];
        #pragma unroll
        for (int fr = 0; fr < 4; ++fr)
            #pragma unroll
            for (int fc = 0; fc < 4; ++fc)
                acc[fr][fc] = (f32x4)(0.0f);

        for (int ds = 0; ds < 8; ++ds) {
            const int d0 = ds * 64;
            __syncthreads();
            #pragma unroll
            for (int s = 0; s < 8; ++s) {
                int i   = s * 256 + t;
                int row = i >> 4, dq = i & 15;
                int kidx = (dq * 4) ^ ((row & 7) << 3);
                float4 va = *(const float4*)&X[(size_t)(xrow0 + row) * DDIM + d0 + dq*4];
                *(uint2*)&As[row*64 + kidx] = pack4_f16(va, 1.0f);
                if (EF16) {
                    uint2 ub = *(const uint2*)&ef[(size_t)(ct*128 + row) * DDIM + d0 + dq*4];
                    *(uint2*)&Bs[row*64 + kidx] = ub;
                } else {
                    float4 vb = *(const float4*)&emb[(size_t)(ct*128 + row) * DDIM + d0 + dq*4];
                    *(uint2*)&Bs[row*64 + kidx] = pack4_f16(vb, ESCALE);
                }
            }
            __syncthreads();
            #pragma unroll
            for (int kk = 0; kk < 2; ++kk) {
                const int kb = kk*32 + (lane >> 4) * 8;
                half8 a[4], b[4];
                #pragma unroll
                for (int fr = 0; fr < 4; ++fr) {
                    int ra = wr*64 + fr*16 + (lane & 15);
                    a[fr] = *(const half8*)&As[ra*64 + (kb ^ ((ra & 7) << 3))];
                }
                #pragma unroll
                for (int fc = 0; fc < 4; ++fc) {
                    int rb = wc*64 + fc*16 + (lane & 15);
                    b[fc] = *(const half8*)&Bs[rb*64 + (kb ^ ((rb & 7) << 3))];
                }
                #pragma unroll
                for (int fr = 0; fr < 4; ++fr)
                    #pragma unroll
                    for (int fc = 0; fc < 4; ++fc)
                        acc[fr][fc] = __builtin_amdgcn_mfma_f32_16x16x32_f16(
                            a[fr], b[fc], acc[fr][fc], 0, 0, 0);
            }
        }

        // ---- epilogue: approx dists, running row-min, candidate append ----
        float eqv[4];
        #pragma unroll
        for (int fc = 0; fc < 4; ++fc)
            eqv[fc] = esq[ct*128 + wc*64 + fc*16 + (lane & 15)];

        #pragma unroll
        for (int fr = 0; fr < 4; ++fr) {
            #pragma unroll
            for (int q = 0; q < 4; ++q) {
                int r = wr*64 + fr*16 + (lane >> 4) * 4 + q;
                float m = INFINITY;
                #pragma unroll
                for (int fc = 0; fc < 4; ++fc) {
                    float dist = (xs[fr*4+q] + eqv[fc]) - EPSC * acc[fr][fc][q];
                    acc[fr][fc][q] = dist;
                    m = fminf(m, dist);
                }
                atomicMin(&rowmin[r], __float_as_uint(m));
            }
        }
        __syncthreads();
        #pragma unroll
        for (int fr = 0; fr < 4; ++fr) {
            #pragma unroll
            for (int q = 0; q < 4; ++q) {
                int r = wr*64 + fr*16 + (lane >> 4) * 4 + q;
                float thr = __uint_as_float(rowmin[r]) + WMARG;
                #pragma unroll
                for (int fc = 0; fc < 4; ++fc) {
                    if (acc[fr][fc][q] <= thr) {
                        int c = ct*128 + wc*64 + fc*16 + (lane & 15);
                        int p = atomicAdd(&ccnt[r], 1);
                        if (p < CAP) cand[r*CAP + p] = (unsigned short)c;
                    }
                }
            }
        }
    }
    __syncthreads();

    // ---- exact f32 rescore of candidates (replicates round-1 fmaf chain) ----
    for (int e = t; e < 128 * CAP; e += 256) {
        int r = e >> 5, s = e & (CAP - 1);
        int cnt = ccnt[r]; if (cnt > CAP) cnt = CAP;
        if (s < cnt) {
            int c = cand[r*CAP + s];
            const float* xp = X   + (size_t)(xrow0 + r) * DDIM;
            const float* ep = emb + (size_t)c * DDIM;
            float acc2 = 0.0f;
            for (int d = 0; d < DDIM; d += 4) {
                float4 xv = *(const float4*)&xp[d];
                float4 ev = *(const float4*)&ep[d];
                acc2 = fmaf(xv.x, ev.x, acc2);
                acc2 = fmaf(xv.y, ev.y, acc2);
                acc2 = fmaf(xv.z, ev.z, acc2);
                acc2 = fmaf(xv.w, ev.w, acc2);
            }
            float dist = (xsq[row0 + r] + esq[c]) - 2.0f * acc2;
            unsigned long long key =
                ((unsigned long long)__float_as_uint(dist) << 32) | (unsigned)c;
            atomicMin(&best[r], key);
        }
    }
    __syncthreads();

    // ---- overflow fallback: full-row exact rescan (expected: never) ----
    for (int r = 0; r < 128; ++r) {
        if (ccnt[r] > CAP) {
            const float* xp = X + (size_t)(xrow0 + r) * DDIM;
            float xse = xsq[row0 + r];
            for (int c = t; c < KC; c += 256) {
                const float* ep = emb + (size_t)c * DDIM;
                float acc2 = 0.0f;
                for (int d = 0; d < DDIM; d += 4) {
                    float4 xv = *(const float4*)&xp[d];
                    float4 ev = *(const float4*)&ep[d];
                    acc2 = fmaf(xv.x, ev.x, acc2);
                    acc2 = fmaf(xv.y, ev.y, acc2);
                    acc2 = fmaf(xv.z, ev.z, acc2);
                    acc2 = fmaf(xv.w, ev.w, acc2);
                }
                float dist = (xse + esq[c]) - 2.0f * acc2;
                unsigned long long key =
                    ((unsigned long long)__float_as_uint(dist) << 32) | (unsigned)c;
                atomicMin(&best[r], key);
            }
        }
    }
    __syncthreads();
    if (t < 128) inds[row0 + t] = (int)(unsigned)(best[t] & 0xffffffffull);
}

// ---------------------------------------------------------------------------
// Kernel 2: gather quantized rows + commitment/KL partials + hist. (unchanged)
// ---------------------------------------------------------------------------
__global__ __launch_bounds__(256) void gather_stats_kernel(
    const float* __restrict__ xmean, const float* __restrict__ xstd,
    const float* __restrict__ emb, const int* __restrict__ inds,
    float* __restrict__ out0, float* __restrict__ out1,
    int* __restrict__ hist,
    double* __restrict__ pc1, double* __restrict__ pc2, double* __restrict__ pkl)
{
    const int blk  = blockIdx.x;
    const int w    = threadIdx.x >> 6;
    const int lane = threadIdx.x & 63;

    float c1 = 0.0f, c2 = 0.0f, kls = 0.0f;

    for (int j = 0; j < 8; j++) {
        int n  = blk * 32 + j * 4 + w;
        int im = inds[n];
        int is = inds[NROWSQ + n];
        if (lane == 0) {
            atomicAdd(&hist[im], 1);
            atomicAdd(&hist[KC + is], 1);
        }
        const float* em = emb  + (size_t)im * DDIM;
        const float* es = emb  + (size_t)is * DDIM;
        const float* xm = xmean + (size_t)n * DDIM;
        const float* xv = xstd  + (size_t)n * DDIM;

        float t1 = 0.0f, t2 = 0.0f;
        float pp = 1.0f, pq = 1.0f;

        #pragma unroll
        for (int half = 0; half < 2; half++) {
            int d = half * 256 + lane * 4;
            float4 q4  = *(const float4*)&em[d];
            float4 m4  = *(const float4*)&xm[d];
            float4 qs4 = *(const float4*)&es[d];
            float4 s4  = *(const float4*)&xv[d];
            float qa[4] = {q4.x, q4.y, q4.z, q4.w};
            float ma[4] = {m4.x, m4.y, m4.z, m4.w};
            float qb[4] = {qs4.x, qs4.y, qs4.z, qs4.w};
            float sa[4] = {s4.x, s4.y, s4.z, s4.w};
            float o0[4], o1[4];
            #pragma unroll
            for (int u = 0; u < 4; u++) {
                float q = qa[u], m = ma[u], s = sa[u], qq = qb[u];
                o0[u] = m + (q - m);
                o1[u] = qq;
                float du = q - m;
                c1 += du * du;
                float dsv = qq - s; c2 += dsv * dsv;
                float sp = s * s, sq = qq * qq;
                float iq = 1.0f / sq;
                t1 += sp * iq;
                t2 += du * du * iq;
                pp *= sp; pq *= sq;
            }
            *(float4*)&out0[(size_t)n * DDIM + d] = make_float4(o0[0], o0[1], o0[2], o0[3]);
            *(float4*)&out1[(size_t)n * DDIM + d] = make_float4(o1[0], o1[1], o1[2], o1[3]);
        }

        #pragma unroll
        for (int off = 1; off < 64; off <<= 1) {
            t1 += __shfl_xor(t1, off);
            t2 += __shfl_xor(t2, off);
            pp *= __shfl_xor(pp, off);
            pq *= __shfl_xor(pq, off);
        }
        if (lane == 0) {
            float term4 = logf(pq + 1e-8f) - logf(pp + 1e-8f);
            float kl = 0.5f * (t1 + t2 - (float)DDIM + term4);
            float klc = kl < 0.0f ? 0.0f : (kl > 10.0f ? 10.0f : kl);
            kls += klc;
        }
    }

    #pragma unroll
    for (int off = 1; off < 64; off <<= 1) {
        c1 += __shfl_xor(c1, off);
        c2 += __shfl_xor(c2, off);
    }
    __shared__ double sc1[4], sc2[4], skl[4];
    if (lane == 0) { sc1[w] = (double)c1; sc2[w] = (double)c2; skl[w] = (double)kls; }
    __syncthreads();
    if (threadIdx.x == 0) {
        pc1[blk] = sc1[0] + sc1[1] + sc1[2] + sc1[3];
        pc2[blk] = sc2[0] + sc2[1] + sc2[2] + sc2[3];
        pkl[blk] = skl[0] + skl[1] + skl[2] + skl[3];
    }
}

// ---------------------------------------------------------------------------
// Kernel 3: finalize scalars. (unchanged)
// ---------------------------------------------------------------------------
__global__ __launch_bounds__(256) void finalize_kernel(
    const int* __restrict__ hist,
    const double* __restrict__ pc1, const double* __restrict__ pc2,
    const double* __restrict__ pkl,
    float* __restrict__ out)
{
    int t = threadIdx.x;
    int w = t >> 6, lane = t & 63;

    double a = 0.0, b = 0.0, c = 0.0;
    for (int i = t; i < 1024; i += 256) { a += pc1[i]; b += pc2[i]; c += pkl[i]; }

    float hm = 0.0f, hs = 0.0f;
    for (int k = t; k < KC; k += 256) {
        float p  = (float)hist[k]      * (1.0f / 32768.0f);
        hm += p * logf(p + 1e-10f);
        float p2 = (float)hist[KC + k] * (1.0f / 32768.0f);
        hs += p2 * logf(p2 + 1e-10f);
    }

    #pragma unroll
    for (int off = 1; off < 64; off <<= 1) {
        a  += __shfl_xor(a, off);
        b  += __shfl_xor(b, off);
        c  += __shfl_xor(c, off);
        hm += __shfl_xor(hm, off);
        hs += __shfl_xor(hs, off);
    }
    __shared__ double sa[4], sb[4], sc[4];
    __shared__ float  sm[4], ss[4];
    if (lane == 0) { sa[w] = a; sb[w] = b; sc[w] = c; sm[w] = hm; ss[w] = hs; }
    __syncthreads();
    if (t == 0) {
        double A = sa[0] + sa[1] + sa[2] + sa[3];
        double B = sb[0] + sb[1] + sb[2] + sb[3];
        double C = sc[0] + sc[1] + sc[2] + sc[3];
        float HM = sm[0] + sm[1] + sm[2] + sm[3];
        float HS = ss[0] + ss[1] + ss[2] + ss[3];
        float mean1 = (float)(A * (1.0 / 16777216.0));
        float mean2 = (float)(B * (1.0 / 16777216.0));
        float commitment = mean1 + mean2;
        float el = (float)(C * (1.0 / 32768.0));
        out[33554432] = commitment * 0.25f + el;   // vq_loss
        out[33554433] = expf(-HM);                 // perplexity_mean
        out[33554434] = expf(-HS);                 // perplexity_std
    }
}

// ---------------------------------------------------------------------------
extern "C" void kernel_launch(void* const* d_in, const int* in_sizes, int n_in,
                              void* d_out, int out_size, void* d_ws, size_t ws_size,
                              hipStream_t stream)
{
    const float* xmean = (const float*)d_in[0];
    const float* xstd  = (const float*)d_in[1];
    const float* emb   = (const float*)d_in[2];
    float* out = (float*)d_out;
    char*  ws  = (char*)d_ws;

    int*    inds = (int*)(ws + WS_INDS);
    int*    hist = (int*)(ws + WS_HIST);
    double* pc1  = (double*)(ws + WS_PC1);
    double* pc2  = (double*)(ws + WS_PC2);
    double* pkl  = (double*)(ws + WS_PKL);
    float*  xsq  = (float*)(ws + WS_XSQ);
    float*  esq  = (float*)(ws + WS_ESQ);
    unsigned short* ef16 = (unsigned short*)(ws + WS_EF16);

    const bool use_ef16 = (ws_size >= (size_t)WS_EF16_END);

    hipMemsetAsync(hist, 0, 2 * KC * sizeof(int), stream);

    rowsq_kernel<<<NROWSQ / 4, 256, 0, stream>>>(xmean, xsq, NROWSQ);
    rowsq_kernel<<<NROWSQ / 4, 256, 0, stream>>>(xstd, xsq + NROWSQ, NROWSQ);
    rowsq_kernel<<<KC / 4, 256, 0, stream>>>(emb, esq, KC);

    if (use_ef16) {
        cvt_e_kernel<<<KC * DDIM / 1024, 256, 0, stream>>>(emb, ef16);
        mfma_argmin_kernel<true><<<RTOT / 128, 256, 0, stream>>>(
            xmean, xstd, emb, ef16, xsq, esq, inds);
    } else {
        mfma_argmin_kernel<false><<<RTOT / 128, 256, 0, stream>>>(
            xmean, xstd, emb, ef16, xsq, esq, inds);
    }

    gather_stats_kernel<<<1024, 256, 0, stream>>>(xmean, xstd, emb, inds,
                                                  out, out + (size_t)NROWSQ * DDIM,
                                                  hist, pc1, pc2, pkl);

    finalize_kernel<<<1, 256, 0, stream>>>(hist, pc1, pc2, pkl, out);
}